// Round 1
// baseline (307.133 us; speedup 1.0000x reference)
//
#include <hip/hip_runtime.h>
#include <hip/hip_bf16.h>
#include <math.h>

// GaussianSelfAttention: B=64, P=256, S=257, D=768, GRID=16.
// Stage 1: qkv[m, 0:2304] = x[m,:] @ [Wq|Wk|Wv]^T + bias  (split-bf16 MFMA, f32 out)
// Stage 2: per (b,s) row: corner sampling, 4-way softmax over q.k_idx, bilinear-weighted V sum.

typedef __attribute__((ext_vector_type(8))) short bf16x8;
typedef __attribute__((ext_vector_type(4))) float f32x4;

#define MTOT 16448   // 64*257
#define DD   768
#define NCOLS 2304

__device__ inline unsigned short f2bf(float f) {
    unsigned u = __float_as_uint(f);
    u += 0x7FFFu + ((u >> 16) & 1u);          // round-to-nearest-even
    return (unsigned short)(u >> 16);
}
__device__ inline float bf2f(unsigned short h) {
    return __uint_as_float(((unsigned)h) << 16);
}

__global__ __launch_bounds__(256) void qkv_gemm(
    const float* __restrict__ x,
    const float* __restrict__ Wq, const float* __restrict__ bq,
    const float* __restrict__ Wk, const float* __restrict__ bk,
    const float* __restrict__ Wv, const float* __restrict__ bv,
    float* __restrict__ qkv)
{
    // 128x128 tile, BK=32, 4 waves in 2x2, each wave 64x64 (4x4 frags of 16x16x32)
    __shared__ __align__(16) unsigned short Ah[128*32];
    __shared__ __align__(16) unsigned short Al[128*32];
    __shared__ __align__(16) unsigned short Bh[128*32];
    __shared__ __align__(16) unsigned short Bl[128*32];

    const int tid   = threadIdx.x;
    const int tileM = blockIdx.x;      // 0..128  (129*128 >= 16448)
    const int tileN = blockIdx.y;      // 0..17   (18*128 = 2304)
    const int which = tileN / 6;       // 0=q,1=k,2=v
    const float* __restrict__ W    = (which == 0) ? Wq : (which == 1) ? Wk : Wv;
    const float* __restrict__ bias = (which == 0) ? bq : (which == 1) ? bk : bv;
    const int wrow0 = (tileN % 6) * 128;
    const bool three = (which < 2);    // q,k need split precision; v doesn't

    const int lane = tid & 63;
    const int wid  = tid >> 6;
    const int wm = wid >> 1, wn = wid & 1;
    const int r16 = lane & 15, kq = lane >> 4;

    const f32x4 zero = {0.f, 0.f, 0.f, 0.f};
    f32x4 acc[4][4];
    #pragma unroll
    for (int i = 0; i < 4; ++i)
        #pragma unroll
        for (int j = 0; j < 4; ++j)
            acc[i][j] = zero;

    for (int kk = 0; kk < 24; ++kk) {
        const int k0 = kk * 32;
        __syncthreads();
        // stage A (x rows) and B (W rows = output cols), f32 -> bf16 hi/lo split
        #pragma unroll
        for (int i = 0; i < 4; ++i) {
            const int e0  = (i * 256 + tid) * 4;   // f32 element index within 128x32 tile
            const int row = e0 >> 5, col = e0 & 31;
            int gm = tileM * 128 + row;
            gm = gm < MTOT ? gm : MTOT - 1;        // clamp; invalid rows discarded at store
            const float4 va = *(const float4*)(x + (size_t)gm * DD + k0 + col);
            const unsigned short h0 = f2bf(va.x), h1 = f2bf(va.y),
                                 h2 = f2bf(va.z), h3 = f2bf(va.w);
            *(ushort4*)(&Ah[row*32 + col]) = make_ushort4(h0, h1, h2, h3);
            *(ushort4*)(&Al[row*32 + col]) = make_ushort4(
                f2bf(va.x - bf2f(h0)), f2bf(va.y - bf2f(h1)),
                f2bf(va.z - bf2f(h2)), f2bf(va.w - bf2f(h3)));
            const float4 vb = *(const float4*)(W + (size_t)(wrow0 + row) * DD + k0 + col);
            const unsigned short g0 = f2bf(vb.x), g1 = f2bf(vb.y),
                                 g2 = f2bf(vb.z), g3 = f2bf(vb.w);
            *(ushort4*)(&Bh[row*32 + col]) = make_ushort4(g0, g1, g2, g3);
            *(ushort4*)(&Bl[row*32 + col]) = make_ushort4(
                f2bf(vb.x - bf2f(g0)), f2bf(vb.y - bf2f(g1)),
                f2bf(vb.z - bf2f(g2)), f2bf(vb.w - bf2f(g3)));
        }
        __syncthreads();

        bf16x8 ah[4], alv[4], bh[4], blv[4];
        #pragma unroll
        for (int i = 0; i < 4; ++i) {
            const int ar = wm*64 + i*16 + r16;
            const int br = wn*64 + i*16 + r16;
            ah[i]  = *(const bf16x8*)(&Ah[ar*32 + kq*8]);
            alv[i] = *(const bf16x8*)(&Al[ar*32 + kq*8]);
            bh[i]  = *(const bf16x8*)(&Bh[br*32 + kq*8]);
            blv[i] = *(const bf16x8*)(&Bl[br*32 + kq*8]);
        }
        #pragma unroll
        for (int i = 0; i < 4; ++i)
            #pragma unroll
            for (int j = 0; j < 4; ++j) {
                acc[i][j] = __builtin_amdgcn_mfma_f32_16x16x32_bf16(ah[i], bh[j], acc[i][j], 0, 0, 0);
                if (three) {
                    acc[i][j] = __builtin_amdgcn_mfma_f32_16x16x32_bf16(ah[i],  blv[j], acc[i][j], 0, 0, 0);
                    acc[i][j] = __builtin_amdgcn_mfma_f32_16x16x32_bf16(alv[i], bh[j],  acc[i][j], 0, 0, 0);
                }
            }
    }

    // epilogue: D element (reg t, lane): row=(lane>>4)*4+t, col=lane&15  [verified mapping]
    #pragma unroll
    for (int i = 0; i < 4; ++i) {
        const int row0 = tileM*128 + wm*64 + i*16 + kq*4;
        #pragma unroll
        for (int j = 0; j < 4; ++j) {
            const int colg = tileN*128 + wn*64 + j*16 + r16;
            const float bb = bias[wrow0 + wn*64 + j*16 + r16];
            #pragma unroll
            for (int t = 0; t < 4; ++t) {
                const int row = row0 + t;
                if (row < MTOT)
                    qkv[(size_t)row * NCOLS + colg] = acc[i][j][t] + bb;
            }
        }
    }
}

// One wave per (b,s) row.
__global__ __launch_bounds__(256) void attn_gather(
    const float* __restrict__ qkv,
    const int*   __restrict__ ids,
    const float* __restrict__ avgs,
    const float* __restrict__ stds,
    const float* __restrict__ nx,
    const float* __restrict__ ny,
    float* __restrict__ out)
{
    const int tid  = threadIdx.x;
    const int lane = tid & 63;
    const int gid  = blockIdx.x * 4 + (tid >> 6);   // 4112*4 = 16448 exactly
    const int b = gid / 257, s = gid % 257;
    float* orow = out + (size_t)gid * DD;

    if (s == 0) {
        // class token: equal scores -> attn=0.25, svf=1, wf=1 -> out = 1.0
        const float4 one = make_float4(1.f, 1.f, 1.f, 1.f);
        #pragma unroll
        for (int j = 0; j < 3; ++j)
            *(float4*)(orow + 4*lane + 256*j) = one;
        return;
    }
    const int p   = s - 1;
    const int img = ids[b];
    const size_t ab = (size_t)img * 512 + p;
    const float a0 = avgs[ab], a1 = avgs[ab + 256];
    const float s0 = stds[ab], s1 = stds[ab + 256];
    const float kx = 7.5f * (1.f + tanhf((nx[b*256 + p] + a0) * s0));
    const float ky = 7.5f * (1.f + tanhf((ny[b*256 + p] + a1) * s1));
    const float kx1 = ceilf(kx), kx2 = floorf(kx);
    const float ky1 = ceilf(ky), ky2 = floorf(ky);
    const float cx[4] = {kx1, kx2, kx1, kx2};
    const float cy[4] = {ky1, ky1, ky2, ky2};
    int   idx[4];
    float w[4];
    #pragma unroll
    for (int n = 0; n < 4; ++n) {
        idx[n] = (int)(16.f * cy[n] + cx[n]);
        w[n]   = (1.f - fabsf(cx[n] - kx)) * (1.f - fabsf(cy[n] - ky));
    }

    const float* qrow = qkv + (size_t)gid * NCOLS;
    float4 qv[3];
    #pragma unroll
    for (int j = 0; j < 3; ++j)
        qv[j] = *(const float4*)(qrow + 4*lane + 256*j);

    float sc[4];
    #pragma unroll
    for (int n = 0; n < 4; ++n) {
        const float* krow = qkv + (size_t)(b*257 + idx[n]) * NCOLS + 768;
        float a = 0.f;
        #pragma unroll
        for (int j = 0; j < 3; ++j) {
            const float4 kv = *(const float4*)(krow + 4*lane + 256*j);
            a += qv[j].x*kv.x + qv[j].y*kv.y + qv[j].z*kv.z + qv[j].w*kv.w;
        }
        sc[n] = a;
    }
    #pragma unroll
    for (int n = 0; n < 4; ++n)
        for (int off = 32; off > 0; off >>= 1)
            sc[n] += __shfl_xor(sc[n], off);

    const float mx = fmaxf(fmaxf(sc[0], sc[1]), fmaxf(sc[2], sc[3]));
    float e0 = expf(sc[0]-mx), e1 = expf(sc[1]-mx), e2 = expf(sc[2]-mx), e3 = expf(sc[3]-mx);
    const float inv = 1.f / (e0 + e1 + e2 + e3);
    const float coef[4] = {e0*inv*w[0], e1*inv*w[1], e2*inv*w[2], e3*inv*w[3]};

    const float* vrow0 = qkv + (size_t)(b*257 + idx[0]) * NCOLS + 1536;
    const float* vrow1 = qkv + (size_t)(b*257 + idx[1]) * NCOLS + 1536;
    const float* vrow2 = qkv + (size_t)(b*257 + idx[2]) * NCOLS + 1536;
    const float* vrow3 = qkv + (size_t)(b*257 + idx[3]) * NCOLS + 1536;
    #pragma unroll
    for (int j = 0; j < 3; ++j) {
        const int d = 4*lane + 256*j;
        float4 v0 = *(const float4*)(vrow0 + d);
        float4 v1 = *(const float4*)(vrow1 + d);
        float4 v2 = *(const float4*)(vrow2 + d);
        float4 v3 = *(const float4*)(vrow3 + d);
        float4 o;
        o.x = coef[0]*v0.x + coef[1]*v1.x + coef[2]*v2.x + coef[3]*v3.x;
        o.y = coef[0]*v0.y + coef[1]*v1.y + coef[2]*v2.y + coef[3]*v3.y;
        o.z = coef[0]*v0.z + coef[1]*v1.z + coef[2]*v2.z + coef[3]*v3.z;
        o.w = coef[0]*v0.w + coef[1]*v1.w + coef[2]*v2.w + coef[3]*v3.w;
        *(float4*)(orow + d) = o;
    }
}

extern "C" void kernel_launch(void* const* d_in, const int* in_sizes, int n_in,
                              void* d_out, int out_size, void* d_ws, size_t ws_size,
                              hipStream_t stream) {
    const float* x    = (const float*)d_in[0];
    const int*   ids  = (const int*)  d_in[1];
    // d_in[2] = mask (unused by reference)
    const float* avgs = (const float*)d_in[3];
    const float* stds = (const float*)d_in[4];
    const float* Wq   = (const float*)d_in[5];
    const float* bq   = (const float*)d_in[6];
    const float* Wk   = (const float*)d_in[7];
    const float* bk   = (const float*)d_in[8];
    const float* Wv   = (const float*)d_in[9];
    const float* bv   = (const float*)d_in[10];
    const float* nx   = (const float*)d_in[11];
    const float* ny   = (const float*)d_in[12];
    float* out = (float*)d_out;
    float* qkv = (float*)d_ws;   // 16448 * 2304 * 4B = 151.6 MB

    dim3 g1(129, 18);
    qkv_gemm<<<g1, 256, 0, stream>>>(x, Wq, bq, Wk, bk, Wv, bv, qkv);
    attn_gather<<<4112, 256, 0, stream>>>(qkv, ids, avgs, stds, nx, ny, out);
}

// Round 2
// 141.500 us; speedup vs baseline: 2.1706x; 2.1706x over previous
//
#include <hip/hip_runtime.h>
#include <math.h>

// GaussianSelfAttention: B=64, P=256, S=257, D=768, GRID=16.
// prepass: x,W -> f16 in MFMA-fragment-permuted tile layout (chunk c = (row&15) + (k>>3)*16 + (row>>4)*64)
// qkv_gemm: 128x128 tile, BK=32, global_load_lds(16B) staging, 16x16x32 f16 MFMA, f16 output + bias
// attn_gather: per-row corner sampling, 4-way softmax, bilinear-weighted V sum (f32 out)

typedef _Float16 f16x8 __attribute__((ext_vector_type(8)));
typedef _Float16 f16x4 __attribute__((ext_vector_type(4)));
typedef float    f32x4 __attribute__((ext_vector_type(4)));

#define MTOT 16448
#define DD   768
#define NC   2304
#define XCH (129*24*512)
#define WCH (18*24*512)

__global__ __launch_bounds__(256) void prepass(
    const float* __restrict__ x,
    const float* __restrict__ Wq, const float* __restrict__ Wk, const float* __restrict__ Wv,
    _Float16* __restrict__ xp, _Float16* __restrict__ wp)
{
    const int gidx = blockIdx.x * 256 + threadIdx.x;
    const float* src;
    _Float16* dst;
    if (gidx < XCH) {
        const int c = gidx & 511, kk = (gidx >> 9) % 24, t = gidx / 12288;
        const int row = ((c >> 6) << 4) + (c & 15);
        int gm = t * 128 + row; gm = gm < MTOT ? gm : MTOT - 1;
        src = x + (size_t)gm * DD + kk * 32 + ((c >> 4) & 3) * 8;
        dst = xp + (size_t)gidx * 8;
    } else {
        const int g = gidx - XCH;
        const int c = g & 511, kk = (g >> 9) % 24, t = g / 12288;
        const int wrow = t * 128 + ((c >> 6) << 4) + (c & 15);   // 0..2303
        const float* W = wrow < 768 ? Wq : (wrow < 1536 ? Wk : Wv);
        const int srow = wrow < 768 ? wrow : (wrow < 1536 ? wrow - 768 : wrow - 1536);
        src = W + (size_t)srow * DD + kk * 32 + ((c >> 4) & 3) * 8;
        dst = wp + (size_t)g * 8;
    }
    const float4 a = *(const float4*)src;
    const float4 b = *(const float4*)(src + 4);
    f16x8 o;
    o[0] = (_Float16)a.x; o[1] = (_Float16)a.y; o[2] = (_Float16)a.z; o[3] = (_Float16)a.w;
    o[4] = (_Float16)b.x; o[5] = (_Float16)b.y; o[6] = (_Float16)b.z; o[7] = (_Float16)b.w;
    *(f16x8*)dst = o;
}

__global__ __launch_bounds__(256) void qkv_gemm(
    const _Float16* __restrict__ xp, const _Float16* __restrict__ wp,
    const float* __restrict__ bq, const float* __restrict__ bk, const float* __restrict__ bv,
    _Float16* __restrict__ qkv)
{
    __shared__ __align__(16) _Float16 Ax[512 * 8];
    __shared__ __align__(16) _Float16 Bx[512 * 8];

    // bijective XCD-chunked swizzle over 2322 blocks; orig is tileM-major so
    // consecutive orig (sharing an A panel) stay on one XCD.
    const int bid = blockIdx.x;
    const int xcd = bid & 7, pos = bid >> 3;
    const int q8 = 2322 / 8, r8 = 2322 % 8;   // 290, 2
    const int orig = (xcd < r8) ? xcd * (q8 + 1) + pos
                                : r8 * (q8 + 1) + (xcd - r8) * q8 + pos;
    const int tileM = orig / 18, tileN = orig % 18;

    const int tid = threadIdx.x, lane = tid & 63, wid = tid >> 6;
    const int wm = wid >> 1, wn = wid & 1;
    const int r16 = lane & 15, kq = lane >> 4;

    const f32x4 zero = {0.f, 0.f, 0.f, 0.f};
    f32x4 acc[4][4];
    #pragma unroll
    for (int i = 0; i < 4; ++i)
        #pragma unroll
        for (int j = 0; j < 4; ++j) acc[i][j] = zero;

    const _Float16* Asrc = xp + (size_t)tileM * 24 * 512 * 8;
    const _Float16* Bsrc = wp + (size_t)tileN * 24 * 512 * 8;

    for (int kk = 0; kk < 24; ++kk) {
        __syncthreads();
        #pragma unroll
        for (int t = 0; t < 2; ++t) {
            const int c0 = t * 256 + wid * 64;           // wave-uniform chunk base
            __builtin_amdgcn_global_load_lds(
                (const __attribute__((address_space(1))) void*)(Asrc + ((size_t)(kk * 512 + c0 + lane)) * 8),
                (__attribute__((address_space(3))) void*)(&Ax[c0 * 8]), 16, 0, 0);
            __builtin_amdgcn_global_load_lds(
                (const __attribute__((address_space(1))) void*)(Bsrc + ((size_t)(kk * 512 + c0 + lane)) * 8),
                (__attribute__((address_space(3))) void*)(&Bx[c0 * 8]), 16, 0, 0);
        }
        __syncthreads();

        f16x8 a[4], b[4];
        #pragma unroll
        for (int i = 0; i < 4; ++i)
            a[i] = *(const f16x8*)(&Ax[((wm * 4 + i) * 64 + lane) * 8]);
        #pragma unroll
        for (int j = 0; j < 4; ++j)
            b[j] = *(const f16x8*)(&Bx[((wn * 4 + j) * 64 + lane) * 8]);
        #pragma unroll
        for (int i = 0; i < 4; ++i)
            #pragma unroll
            for (int j = 0; j < 4; ++j)
                acc[i][j] = __builtin_amdgcn_mfma_f32_16x16x32_f16(a[i], b[j], acc[i][j], 0, 0, 0);
    }

    const int sec = tileN / 6;
    const float* bias = sec == 0 ? bq : (sec == 1 ? bk : bv);
    const int bcol0 = (tileN % 6) * 128 + wn * 64;
    #pragma unroll
    for (int i = 0; i < 4; ++i) {
        const int row0 = tileM * 128 + wm * 64 + i * 16 + kq * 4;
        #pragma unroll
        for (int j = 0; j < 4; ++j) {
            const int col = tileN * 128 + wn * 64 + j * 16 + r16;
            const float bb = bias[bcol0 + j * 16 + r16];
            #pragma unroll
            for (int t = 0; t < 4; ++t) {
                const int row = row0 + t;
                if (row < MTOT)
                    qkv[(size_t)row * NC + col] = (_Float16)(acc[i][j][t] + bb);
            }
        }
    }
}

__global__ __launch_bounds__(256) void attn_gather(
    const _Float16* __restrict__ qkv,
    const int*   __restrict__ ids,
    const float* __restrict__ avgs,
    const float* __restrict__ stds,
    const float* __restrict__ nx,
    const float* __restrict__ ny,
    float* __restrict__ out)
{
    const int tid  = threadIdx.x;
    const int lane = tid & 63;
    const int gid  = blockIdx.x * 4 + (tid >> 6);   // 4112*4 = 16448
    const int b = gid / 257, s = gid % 257;
    float* orow = out + (size_t)gid * DD;

    if (s == 0) {
        const float4 one = make_float4(1.f, 1.f, 1.f, 1.f);
        #pragma unroll
        for (int j = 0; j < 3; ++j)
            *(float4*)(orow + 4 * lane + 256 * j) = one;
        return;
    }
    const int p   = s - 1;
    const int img = ids[b];
    const size_t ab = (size_t)img * 512 + p;
    const float a0 = avgs[ab], a1 = avgs[ab + 256];
    const float s0 = stds[ab], s1 = stds[ab + 256];
    const float kx = 7.5f * (1.f + tanhf((nx[b * 256 + p] + a0) * s0));
    const float ky = 7.5f * (1.f + tanhf((ny[b * 256 + p] + a1) * s1));
    const float kx1 = ceilf(kx), kx2 = floorf(kx);
    const float ky1 = ceilf(ky), ky2 = floorf(ky);
    const float cx[4] = {kx1, kx2, kx1, kx2};
    const float cy[4] = {ky1, ky1, ky2, ky2};
    int   idx[4];
    float w[4];
    #pragma unroll
    for (int n = 0; n < 4; ++n) {
        idx[n] = (int)(16.f * cy[n] + cx[n]);
        w[n]   = (1.f - fabsf(cx[n] - kx)) * (1.f - fabsf(cy[n] - ky));
    }

    const _Float16* qrow = qkv + (size_t)gid * NC;
    float qf[12];
    #pragma unroll
    for (int j = 0; j < 3; ++j) {
        const f16x4 v = *(const f16x4*)(qrow + lane * 4 + j * 256);
        qf[4 * j + 0] = (float)v[0]; qf[4 * j + 1] = (float)v[1];
        qf[4 * j + 2] = (float)v[2]; qf[4 * j + 3] = (float)v[3];
    }

    float sc[4];
    #pragma unroll
    for (int n = 0; n < 4; ++n) {
        const _Float16* krow = qkv + (size_t)(b * 257 + idx[n]) * NC + 768;
        float a = 0.f;
        #pragma unroll
        for (int j = 0; j < 3; ++j) {
            const f16x4 kv = *(const f16x4*)(krow + lane * 4 + j * 256);
            a += qf[4 * j + 0] * (float)kv[0] + qf[4 * j + 1] * (float)kv[1]
               + qf[4 * j + 2] * (float)kv[2] + qf[4 * j + 3] * (float)kv[3];
        }
        sc[n] = a;
    }
    #pragma unroll
    for (int n = 0; n < 4; ++n)
        for (int off = 32; off > 0; off >>= 1)
            sc[n] += __shfl_xor(sc[n], off);

    const float mx = fmaxf(fmaxf(sc[0], sc[1]), fmaxf(sc[2], sc[3]));
    const float e0 = expf(sc[0] - mx), e1 = expf(sc[1] - mx),
                e2 = expf(sc[2] - mx), e3 = expf(sc[3] - mx);
    const float inv = 1.f / (e0 + e1 + e2 + e3);
    const float coef[4] = {e0 * inv * w[0], e1 * inv * w[1], e2 * inv * w[2], e3 * inv * w[3]};

    const _Float16* vr0 = qkv + (size_t)(b * 257 + idx[0]) * NC + 1536;
    const _Float16* vr1 = qkv + (size_t)(b * 257 + idx[1]) * NC + 1536;
    const _Float16* vr2 = qkv + (size_t)(b * 257 + idx[2]) * NC + 1536;
    const _Float16* vr3 = qkv + (size_t)(b * 257 + idx[3]) * NC + 1536;
    #pragma unroll
    for (int j = 0; j < 3; ++j) {
        const int d = lane * 4 + j * 256;
        const f16x4 v0 = *(const f16x4*)(vr0 + d);
        const f16x4 v1 = *(const f16x4*)(vr1 + d);
        const f16x4 v2 = *(const f16x4*)(vr2 + d);
        const f16x4 v3 = *(const f16x4*)(vr3 + d);
        float4 o;
        o.x = coef[0] * (float)v0[0] + coef[1] * (float)v1[0] + coef[2] * (float)v2[0] + coef[3] * (float)v3[0];
        o.y = coef[0] * (float)v0[1] + coef[1] * (float)v1[1] + coef[2] * (float)v2[1] + coef[3] * (float)v3[1];
        o.z = coef[0] * (float)v0[2] + coef[1] * (float)v1[2] + coef[2] * (float)v2[2] + coef[3] * (float)v3[2];
        o.w = coef[0] * (float)v0[3] + coef[1] * (float)v1[3] + coef[2] * (float)v2[3] + coef[3] * (float)v3[3];
        *(float4*)(orow + d) = o;
    }
}

extern "C" void kernel_launch(void* const* d_in, const int* in_sizes, int n_in,
                              void* d_out, int out_size, void* d_ws, size_t ws_size,
                              hipStream_t stream) {
    const float* x    = (const float*)d_in[0];
    const int*   ids  = (const int*)  d_in[1];
    const float* avgs = (const float*)d_in[3];
    const float* stds = (const float*)d_in[4];
    const float* Wq   = (const float*)d_in[5];
    const float* bq   = (const float*)d_in[6];
    const float* Wk   = (const float*)d_in[7];
    const float* bk   = (const float*)d_in[8];
    const float* Wv   = (const float*)d_in[9];
    const float* bv   = (const float*)d_in[10];
    const float* nx   = (const float*)d_in[11];
    const float* ny   = (const float*)d_in[12];
    float* out = (float*)d_out;

    char* ws = (char*)d_ws;
    _Float16* qkv = (_Float16*)ws;                              // 75,792,384 B
    _Float16* xp  = (_Float16*)(ws + 75792384);                 // 25,362,432 B
    _Float16* wp  = (_Float16*)(ws + 75792384 + 25362432);      //  3,538,944 B

    prepass<<<(XCH + WCH) / 256, 256, 0, stream>>>(x, Wq, Wk, Wv, xp, wp);
    qkv_gemm<<<2322, 256, 0, stream>>>(xp, wp, bq, bk, bv, qkv);
    attn_gather<<<4112, 256, 0, stream>>>(qkv, ids, avgs, stds, nx, ny, out);
}

// Round 3
// 133.348 us; speedup vs baseline: 2.3032x; 1.0611x over previous
//
#include <hip/hip_runtime.h>
#include <math.h>

// GaussianSelfAttention: B=64, P=256, S=257, D=768, GRID=16.
// prepass: x,W -> f16 in MFMA-fragment-permuted unit layout (16B unit per (mblk,ksub,lane))
// qkv_gemm: 128x128 tile, BK=64, depth-2 counted-vmcnt pipeline, raw barriers, f16 MFMA
// attn_gather: per-row corner sampling, 4-way softmax, bilinear-weighted V sum (f32 out)

typedef _Float16 f16x8 __attribute__((ext_vector_type(8)));
typedef _Float16 f16x4 __attribute__((ext_vector_type(4)));
typedef float    f32x4 __attribute__((ext_vector_type(4)));

#define MTOT 16448
#define DD   768
#define NC   2304
#define NT   12                 // K-steps of 64
#define XU   (129*12*1024)      // x units (16B each)
#define WU   (18*12*1024)       // w units

__global__ __launch_bounds__(256) void prepass(
    const float* __restrict__ x,
    const float* __restrict__ Wq, const float* __restrict__ Wk, const float* __restrict__ Wv,
    _Float16* __restrict__ xp, _Float16* __restrict__ wp)
{
    const int gidx = blockIdx.x * 256 + threadIdx.x;
    const float* src;
    _Float16* dst;
    if (gidx < XU) {
        const int u = gidx & 1023, k = (gidx >> 10) % NT, tile = gidx / (NT * 1024);
        const int lane = u & 63, ksub = (u >> 6) & 1, mblk = u >> 7;
        int row = tile * 128 + mblk * 16 + (lane & 15);
        row = row < MTOT ? row : MTOT - 1;
        const int col = k * 64 + ksub * 32 + (lane >> 4) * 8;
        src = x + (size_t)row * DD + col;
        dst = xp + (size_t)gidx * 8;
    } else {
        const int g = gidx - XU;
        const int u = g & 1023, k = (g >> 10) % NT, tile = g / (NT * 1024);
        const int lane = u & 63, ksub = (u >> 6) & 1, mblk = u >> 7;
        const int wrow = tile * 128 + mblk * 16 + (lane & 15);      // 0..2303
        const float* W = wrow < 768 ? Wq : (wrow < 1536 ? Wk : Wv);
        const int srow = wrow - (wrow < 768 ? 0 : (wrow < 1536 ? 768 : 1536));
        const int col = k * 64 + ksub * 32 + (lane >> 4) * 8;
        src = W + (size_t)srow * DD + col;
        dst = wp + (size_t)g * 8;
    }
    const float4 a = *(const float4*)src;
    const float4 b = *(const float4*)(src + 4);
    f16x8 o;
    o[0] = (_Float16)a.x; o[1] = (_Float16)a.y; o[2] = (_Float16)a.z; o[3] = (_Float16)a.w;
    o[4] = (_Float16)b.x; o[5] = (_Float16)b.y; o[6] = (_Float16)b.z; o[7] = (_Float16)b.w;
    *(f16x8*)dst = o;
}

__global__ __launch_bounds__(256) void qkv_gemm(
    const _Float16* __restrict__ xp, const _Float16* __restrict__ wp,
    const float* __restrict__ bq, const float* __restrict__ bk, const float* __restrict__ bv,
    _Float16* __restrict__ qkv)
{
    __shared__ __align__(16) _Float16 Ax[2][8192];   // [dbuf][1024 units * 8]
    __shared__ __align__(16) _Float16 Bx[2][8192];

    // bijective XCD-chunked swizzle over 2322 blocks, tileM-major
    const int bid = blockIdx.x;
    const int xcd = bid & 7, pos = bid >> 3;
    const int q8 = 2322 / 8, r8 = 2322 % 8;          // 290, 2
    const int orig = (xcd < r8) ? xcd * (q8 + 1) + pos
                                : r8 * (q8 + 1) + (xcd - r8) * q8 + pos;
    const int tileM = orig / 18, tileN = orig % 18;

    const int tid = threadIdx.x, lane = tid & 63, wid = tid >> 6;
    const int wm = wid >> 1, wn = wid & 1;
    const int r16 = lane & 15, kq = lane >> 4;

    const _Float16* Asrc = xp + (size_t)tileM * NT * 8192;
    const _Float16* Bsrc = wp + (size_t)tileN * NT * 8192;

    const f32x4 zero = {0.f, 0.f, 0.f, 0.f};
    f32x4 acc[4][4];
    #pragma unroll
    for (int i = 0; i < 4; ++i)
        #pragma unroll
        for (int j = 0; j < 4; ++j) acc[i][j] = zero;

    // prologue: stage K-step 0 into buf 0
    #pragma unroll
    for (int g = 0; g < 4; ++g) {
        const int u = g * 256 + tid;
        __builtin_amdgcn_global_load_lds(
            (const __attribute__((address_space(1))) void*)(Asrc + (size_t)u * 8),
            (__attribute__((address_space(3))) void*)(&Ax[0][u * 8]), 16, 0, 0);
        __builtin_amdgcn_global_load_lds(
            (const __attribute__((address_space(1))) void*)(Bsrc + (size_t)u * 8),
            (__attribute__((address_space(3))) void*)(&Bx[0][u * 8]), 16, 0, 0);
    }

    for (int t = 0; t < NT; ++t) {
        const int cur = t & 1;
        if (t + 1 < NT) {
            // stage next K-step into the other buffer (8 loads stay in flight)
            const size_t off = (size_t)(t + 1) * 8192;
            #pragma unroll
            for (int g = 0; g < 4; ++g) {
                const int u = g * 256 + tid;
                __builtin_amdgcn_global_load_lds(
                    (const __attribute__((address_space(1))) void*)(Asrc + off + (size_t)u * 8),
                    (__attribute__((address_space(3))) void*)(&Ax[cur ^ 1][u * 8]), 16, 0, 0);
                __builtin_amdgcn_global_load_lds(
                    (const __attribute__((address_space(1))) void*)(Bsrc + off + (size_t)u * 8),
                    (__attribute__((address_space(3))) void*)(&Bx[cur ^ 1][u * 8]), 16, 0, 0);
            }
            asm volatile("s_waitcnt vmcnt(8)" ::: "memory");   // wait only buf[cur]'s loads
        } else {
            asm volatile("s_waitcnt vmcnt(0)" ::: "memory");
        }
        __builtin_amdgcn_s_barrier();          // buf[cur] staged by ALL threads
        __builtin_amdgcn_sched_barrier(0);     // no ds_read hoists above the barrier

        #pragma unroll
        for (int s = 0; s < 2; ++s) {
            f16x8 a[4], b[4];
            #pragma unroll
            for (int i = 0; i < 4; ++i)
                a[i] = *(const f16x8*)(&Ax[cur][(((wm * 4 + i) * 2 + s) * 64 + lane) * 8]);
            #pragma unroll
            for (int j = 0; j < 4; ++j)
                b[j] = *(const f16x8*)(&Bx[cur][(((wn * 4 + j) * 2 + s) * 64 + lane) * 8]);
            #pragma unroll
            for (int i = 0; i < 4; ++i)
                #pragma unroll
                for (int j = 0; j < 4; ++j)
                    acc[i][j] = __builtin_amdgcn_mfma_f32_16x16x32_f16(a[i], b[j], acc[i][j], 0, 0, 0);
        }
        asm volatile("s_waitcnt lgkmcnt(0)" ::: "memory");  // all ds_reads of buf[cur] done
        __builtin_amdgcn_sched_barrier(0);
        __builtin_amdgcn_s_barrier();          // safe to overwrite buf[cur] next iter
        __builtin_amdgcn_sched_barrier(0);
    }

    const int sec = tileN / 6;
    const float* bias = sec == 0 ? bq : (sec == 1 ? bk : bv);
    const int bcol0 = (tileN % 6) * 128 + wn * 64;
    #pragma unroll
    for (int i = 0; i < 4; ++i) {
        const int row0 = tileM * 128 + wm * 64 + i * 16 + kq * 4;
        #pragma unroll
        for (int j = 0; j < 4; ++j) {
            const int col = tileN * 128 + wn * 64 + j * 16 + r16;
            const float bb = bias[bcol0 + j * 16 + r16];
            #pragma unroll
            for (int t = 0; t < 4; ++t) {
                const int row = row0 + t;
                if (row < MTOT)
                    qkv[(size_t)row * NC + col] = (_Float16)(acc[i][j][t] + bb);
            }
        }
    }
}

__global__ __launch_bounds__(256) void attn_gather(
    const _Float16* __restrict__ qkv,
    const int*   __restrict__ ids,
    const float* __restrict__ avgs,
    const float* __restrict__ stds,
    const float* __restrict__ nx,
    const float* __restrict__ ny,
    float* __restrict__ out)
{
    const int tid  = threadIdx.x;
    const int lane = tid & 63;
    // XCD-chunked bijective swizzle (4112 = 8*514): each XCD gets 8 consecutive b's
    const int bid = blockIdx.x;
    const int swz = (bid & 7) * 514 + (bid >> 3);
    const int gid = swz * 4 + (tid >> 6);
    const int b = gid / 257, s = gid % 257;
    float* orow = out + (size_t)gid * DD;

    if (s == 0) {
        const float4 one = make_float4(1.f, 1.f, 1.f, 1.f);
        #pragma unroll
        for (int j = 0; j < 3; ++j)
            *(float4*)(orow + 4 * lane + 256 * j) = one;
        return;
    }
    const int p   = s - 1;
    const int img = ids[b];
    const size_t ab = (size_t)img * 512 + p;
    const float a0 = avgs[ab], a1 = avgs[ab + 256];
    const float s0 = stds[ab], s1 = stds[ab + 256];
    const float kx = 7.5f * (1.f + tanhf((nx[b * 256 + p] + a0) * s0));
    const float ky = 7.5f * (1.f + tanhf((ny[b * 256 + p] + a1) * s1));
    const float kx1 = ceilf(kx), kx2 = floorf(kx);
    const float ky1 = ceilf(ky), ky2 = floorf(ky);
    const float cx[4] = {kx1, kx2, kx1, kx2};
    const float cy[4] = {ky1, ky1, ky2, ky2};
    int   idx[4];
    float w[4];
    #pragma unroll
    for (int n = 0; n < 4; ++n) {
        idx[n] = (int)(16.f * cy[n] + cx[n]);
        w[n]   = (1.f - fabsf(cx[n] - kx)) * (1.f - fabsf(cy[n] - ky));
    }

    const _Float16* qrow = qkv + (size_t)gid * NC;
    float qf[12];
    #pragma unroll
    for (int j = 0; j < 3; ++j) {
        const f16x4 v = *(const f16x4*)(qrow + lane * 4 + j * 256);
        qf[4 * j + 0] = (float)v[0]; qf[4 * j + 1] = (float)v[1];
        qf[4 * j + 2] = (float)v[2]; qf[4 * j + 3] = (float)v[3];
    }

    float sc[4];
    #pragma unroll
    for (int n = 0; n < 4; ++n) {
        const _Float16* krow = qkv + (size_t)(b * 257 + idx[n]) * NC + 768;
        float a = 0.f;
        #pragma unroll
        for (int j = 0; j < 3; ++j) {
            const f16x4 kv = *(const f16x4*)(krow + lane * 4 + j * 256);
            a += qf[4 * j + 0] * (float)kv[0] + qf[4 * j + 1] * (float)kv[1]
               + qf[4 * j + 2] * (float)kv[2] + qf[4 * j + 3] * (float)kv[3];
        }
        sc[n] = a;
    }
    #pragma unroll
    for (int n = 0; n < 4; ++n)
        for (int off = 32; off > 0; off >>= 1)
            sc[n] += __shfl_xor(sc[n], off);

    const float mx = fmaxf(fmaxf(sc[0], sc[1]), fmaxf(sc[2], sc[3]));
    const float e0 = expf(sc[0] - mx), e1 = expf(sc[1] - mx),
                e2 = expf(sc[2] - mx), e3 = expf(sc[3] - mx);
    const float inv = 1.f / (e0 + e1 + e2 + e3);
    const float coef[4] = {e0 * inv * w[0], e1 * inv * w[1], e2 * inv * w[2], e3 * inv * w[3]};

    const _Float16* vr0 = qkv + (size_t)(b * 257 + idx[0]) * NC + 1536;
    const _Float16* vr1 = qkv + (size_t)(b * 257 + idx[1]) * NC + 1536;
    const _Float16* vr2 = qkv + (size_t)(b * 257 + idx[2]) * NC + 1536;
    const _Float16* vr3 = qkv + (size_t)(b * 257 + idx[3]) * NC + 1536;
    #pragma unroll
    for (int j = 0; j < 3; ++j) {
        const int d = lane * 4 + j * 256;
        const f16x4 v0 = *(const f16x4*)(vr0 + d);
        const f16x4 v1 = *(const f16x4*)(vr1 + d);
        const f16x4 v2 = *(const f16x4*)(vr2 + d);
        const f16x4 v3 = *(const f16x4*)(vr3 + d);
        float4 o;
        o.x = coef[0] * (float)v0[0] + coef[1] * (float)v1[0] + coef[2] * (float)v2[0] + coef[3] * (float)v3[0];
        o.y = coef[0] * (float)v0[1] + coef[1] * (float)v1[1] + coef[2] * (float)v2[1] + coef[3] * (float)v3[1];
        o.z = coef[0] * (float)v0[2] + coef[1] * (float)v1[2] + coef[2] * (float)v2[2] + coef[3] * (float)v3[2];
        o.w = coef[0] * (float)v0[3] + coef[1] * (float)v1[3] + coef[2] * (float)v2[3] + coef[3] * (float)v3[3];
        *(float4*)(orow + d) = o;
    }
}

extern "C" void kernel_launch(void* const* d_in, const int* in_sizes, int n_in,
                              void* d_out, int out_size, void* d_ws, size_t ws_size,
                              hipStream_t stream) {
    const float* x    = (const float*)d_in[0];
    const int*   ids  = (const int*)  d_in[1];
    const float* avgs = (const float*)d_in[3];
    const float* stds = (const float*)d_in[4];
    const float* Wq   = (const float*)d_in[5];
    const float* bq   = (const float*)d_in[6];
    const float* Wk   = (const float*)d_in[7];
    const float* bk   = (const float*)d_in[8];
    const float* Wv   = (const float*)d_in[9];
    const float* bv   = (const float*)d_in[10];
    const float* nx   = (const float*)d_in[11];
    const float* ny   = (const float*)d_in[12];
    float* out = (float*)d_out;

    char* ws = (char*)d_ws;
    _Float16* qkv = (_Float16*)ws;                              // 75,792,384 B
    _Float16* xp  = (_Float16*)(ws + 75792384);                 // 25,362,432 B
    _Float16* wp  = (_Float16*)(ws + 75792384 + 25362432);      //  3,538,944 B

    prepass<<<(XU + WU) / 256, 256, 0, stream>>>(x, Wq, Wk, Wv, xp, wp);
    qkv_gemm<<<2322, 256, 0, stream>>>(xp, wp, bq, bk, bv, qkv);
    attn_gather<<<4112, 256, 0, stream>>>(qkv, ids, avgs, stds, nx, ny, out);
}